// Round 1
// baseline (59.262 us; speedup 1.0000x reference)
//
#include <hip/hip_runtime.h>

// roi_align_inv, gather formulation.
// out[n, y, x] = bilinear(pool_dams[n], u(x), v(y)) if (y,x) inside the ROI's
// 96x96 grid window and indices valid, else 0. Every output element written
// exactly once -> no zeroing pass needed.

#define MAP_H 168
#define MAP_W 168
#define GRID_H 96
#define GRID_W 96
#define POOLW 7
#define HW (MAP_H * MAP_W)        // 28224
#define QUADS (HW / 4)            // 7056 float4 per ROI
#define QROW (MAP_W / 4)          // 42 float4 per row

__global__ __launch_bounds__(256) void roi_inv_kernel(
    const float* __restrict__ pool_dams,   // [N,7,7]
    const float* __restrict__ rois,        // [N,4] x1,y1,x2,y2
    float* __restrict__ out)               // [N,168,168]
{
    const int n = blockIdx.y;

    __shared__ float pf[49];
    __shared__ float sroi[4];
    if (threadIdx.x < 49) pf[threadIdx.x] = pool_dams[n * 49 + threadIdx.x];
    if (threadIdx.x < 4)  sroi[threadIdx.x] = rois[n * 4 + threadIdx.x];
    __syncthreads();

    const int t = blockIdx.x * blockDim.x + threadIdx.x;
    if (t >= QUADS) return;

    // clip rois exactly as reference
    const float x1 = fminf(fmaxf(sroi[0], 0.0f), (float)(MAP_W - 1));
    const float y1 = fminf(fmaxf(sroi[1], 0.0f), (float)(MAP_H - 1));
    const float x2 = fminf(fmaxf(sroi[2], 0.0f), (float)(MAP_W - 1));
    const float y2 = fminf(fmaxf(sroi[3], 0.0f), (float)(MAP_H - 1));
    const int   ixl = (int)floorf(x1);
    const int   iyl = (int)floorf(y1);
    const float dw = x2 - x1;
    const float dh = y2 - y1;

    const int y  = t / QROW;
    const int x0 = (t - y * QROW) * 4;

    float rv[4] = {0.0f, 0.0f, 0.0f, 0.0f};

    const int dy = y - iyl;
    if (dy >= 0 && dy < GRID_H) {
        // v: replicate reference op order bitwise: (gy - y1) / (y2 - y1) * 6
        const float v  = (float)y == 0.0f ? (0.0f - y1) / dh * 6.0f
                                          : ((float)y - y1) / dh * 6.0f;
        const float vl = floorf(v);
        const float vh = ceilf(v);
        const bool  vvalid = (vl >= 0.0f) && (vl < (float)POOLW) &&
                             (vh >= 0.0f) && (vh < (float)POOLW);
        const float yw = v - vl;

#pragma unroll
        for (int k = 0; k < 4; ++k) {
            const int x  = x0 + k;
            const int dx = x - ixl;
            if (dx >= 0 && dx < GRID_W) {
                const float u  = ((float)x - x1) / dw * 6.0f;
                const float ul = floorf(u);
                const float uh = ceilf(u);
                const bool valid = vvalid &&
                                   (ul >= 0.0f) && (ul < (float)POOLW) &&
                                   (uh >= 0.0f) && (uh < (float)POOLW);
                const float xw = v - v; // placeholder removed below
                (void)xw;
                const float xww = u - ul;
                // loc = clip(int(iy*7+ix), 0, 48) — float mul/add then trunc-cast
                int l_ll = (int)(vl * 7.0f + ul);
                int l_lh = (int)(vl * 7.0f + uh);
                int l_hl = (int)(vh * 7.0f + ul);
                int l_hh = (int)(vh * 7.0f + uh);
                l_ll = min(max(l_ll, 0), 48);
                l_lh = min(max(l_lh, 0), 48);
                l_hl = min(max(l_hl, 0), 48);
                l_hh = min(max(l_hh, 0), 48);
                float val = pf[l_ll] * (1.0f - xww) * (1.0f - yw)
                          + pf[l_lh] * xww          * (1.0f - yw)
                          + pf[l_hl] * (1.0f - xww) * yw
                          + pf[l_hh] * xww          * yw;
                rv[k] = valid ? val : 0.0f;
            }
        }
    }

    float4* op = (float4*)(out + (size_t)n * HW);
    op[t] = make_float4(rv[0], rv[1], rv[2], rv[3]);
}

extern "C" void kernel_launch(void* const* d_in, const int* in_sizes, int n_in,
                              void* d_out, int out_size, void* d_ws, size_t ws_size,
                              hipStream_t stream) {
    const float* pool_dams = (const float*)d_in[0];
    const float* rois      = (const float*)d_in[1];
    float* out = (float*)d_out;

    const int n_rois = in_sizes[0] / 49;   // 2048
    dim3 grid((QUADS + 255) / 256, n_rois);
    roi_inv_kernel<<<grid, 256, 0, stream>>>(pool_dams, rois, out);
}

// Round 2
// 39.067 us; speedup vs baseline: 1.5169x; 1.5169x over previous
//
#include <hip/hip_runtime.h>

// roi_align_inv, gather formulation with per-ROI separable precompute.
// One block per ROI:
//   Phase A: per-column u-interp weights/indices (168 divs) + per-row v-info (168 divs)
//   Phase B: cinterp[7][168] = x-interpolated pool rows
//   Phase C: out[y][x0..x0+3] = cinterp[iyl][x]*rw0 + cinterp[iyh][x]*rw1  (float4)

#define MAP_H 168
#define MAP_W 168
#define POOLW 7
#define HW (MAP_H * MAP_W)        // 28224
#define QUADS (HW / 4)            // 7056
#define QROW (MAP_W / 4)          // 42

__global__ __launch_bounds__(256) void roi_inv_kernel(
    const float* __restrict__ pool_dams,   // [N,7,7]
    const float* __restrict__ rois,        // [N,4]
    float* __restrict__ out)               // [N,168,168]
{
    const int n   = blockIdx.x;
    const int tid = threadIdx.x;

    __shared__ float  pf[49];
    __shared__ float  cw0[MAP_W], cw1[MAP_W];
    __shared__ int    cpk[MAP_W];
    __shared__ float4 rowt[MAP_H];               // {rw0, rw1, off_l(bits), off_h(bits)}
    __shared__ float  cinterp[POOLW * MAP_W];    // [7][168]

    if (tid < 49) pf[tid] = pool_dams[n * 49 + tid];

    // uniform roi load (L2/L3 cached, broadcast)
    const float x1 = fminf(fmaxf(rois[n * 4 + 0], 0.0f), (float)(MAP_W - 1));
    const float y1 = fminf(fmaxf(rois[n * 4 + 1], 0.0f), (float)(MAP_H - 1));
    const float x2 = fminf(fmaxf(rois[n * 4 + 2], 0.0f), (float)(MAP_W - 1));
    const float y2 = fminf(fmaxf(rois[n * 4 + 3], 0.0f), (float)(MAP_H - 1));
    const float dw = x2 - x1;
    const float dh = y2 - y1;

    if (tid < MAP_W) {
        // ---- column (x) entry: exact reference op order (gx - x1)/dw * 6 ----
        {
            const float u  = ((float)tid - x1) / dw * 6.0f;
            const float ul = floorf(u), uh = ceilf(u);
            const bool  uvalid = (ul >= 0.0f) && (uh < (float)POOLW); // implies other two
            const float xw = u - ul;
            const int ixl = min(max((int)ul, 0), POOLW - 1);
            const int ixh = min(max((int)uh, 0), POOLW - 1);
            cw0[tid] = uvalid ? (1.0f - xw) : 0.0f;
            cw1[tid] = uvalid ? xw          : 0.0f;
            cpk[tid] = ixl | (ixh << 8);
        }
        // ---- row (y) entry ----
        {
            const float v  = ((float)tid - y1) / dh * 6.0f;
            const float vl = floorf(v), vh = ceilf(v);
            const bool  vvalid = (vl >= 0.0f) && (vh < (float)POOLW);
            const float yw = v - vl;
            const int iyl = min(max((int)vl, 0), POOLW - 1);
            const int iyh = min(max((int)vh, 0), POOLW - 1);
            float4 rt;
            rt.x = vvalid ? (1.0f - yw) : 0.0f;
            rt.y = vvalid ? yw          : 0.0f;
            rt.z = __int_as_float(iyl * MAP_W);  // element offset into cinterp
            rt.w = __int_as_float(iyh * MAP_W);
            rowt[tid] = rt;
        }
    }
    __syncthreads();

    if (tid < MAP_W) {
        const float w0 = cw0[tid];
        const float w1 = cw1[tid];
        const int   pk = cpk[tid];
        const int ixl = pk & 0xff;
        const int ixh = pk >> 8;
#pragma unroll
        for (int r = 0; r < POOLW; ++r)
            cinterp[r * MAP_W + tid] = pf[r * POOLW + ixl] * w0 + pf[r * POOLW + ixh] * w1;
    }
    __syncthreads();

    float4* op = (float4*)(out + (size_t)n * HW);
#pragma unroll 4
    for (int qi = tid; qi < QUADS; qi += 256) {
        const int y  = qi / QROW;            // magic-number div by 42
        const int xq = qi - y * QROW;
        const float4 rt = rowt[y];
        const int o0 = __float_as_int(rt.z);
        const int o1 = __float_as_int(rt.w);
        const float4 a = ((const float4*)(cinterp + o0))[xq];  // 672B row stride, 16B aligned
        const float4 b = ((const float4*)(cinterp + o1))[xq];
        float4 r;
        r.x = a.x * rt.x + b.x * rt.y;
        r.y = a.y * rt.x + b.y * rt.y;
        r.z = a.z * rt.x + b.z * rt.y;
        r.w = a.w * rt.x + b.w * rt.y;
        op[qi] = r;
    }
}

extern "C" void kernel_launch(void* const* d_in, const int* in_sizes, int n_in,
                              void* d_out, int out_size, void* d_ws, size_t ws_size,
                              hipStream_t stream) {
    const float* pool_dams = (const float*)d_in[0];
    const float* rois      = (const float*)d_in[1];
    float* out = (float*)d_out;

    const int n_rois = in_sizes[0] / 49;   // 2048
    roi_inv_kernel<<<dim3(n_rois), 256, 0, stream>>>(pool_dams, rois, out);
}